// Round 1
// baseline (387.245 us; speedup 1.0000x reference)
//
#include <hip/hip_runtime.h>

// Problem: B=64, H=W=32, HW=1024. steps = 256, backtrack iters = 255.
// Outputs concatenated: [histories 65536][paths 65536][pred_cost 65536] float32.

#define HW 1024

// ---------------- conv1 (2->32 ch, 3x3 SAME) + ReLU ----------------
__global__ __launch_bounds__(256) void conv1_relu(
    const float* __restrict__ maps, const float* __restrict__ start,
    const float* __restrict__ goal, const float* __restrict__ w1,
    const float* __restrict__ b1, float* __restrict__ hbuf) {
  int tid = blockIdx.x * 256 + threadIdx.x;       // 64*32*1024 threads
  int pix = tid & 1023;
  int oc  = (tid >> 10) & 31;
  int b   = tid >> 15;
  int y = pix >> 5, x = pix & 31;
  const float* m = maps  + b * HW;
  const float* s = start + b * HW;
  const float* g = goal  + b * HW;
  const float* w = w1 + oc * 18;                  // (oc, c, ky, kx)
  float acc = b1[oc];
  #pragma unroll
  for (int ky = 0; ky < 3; ++ky) {
    int yy = y + ky - 1;
    if (yy < 0 || yy > 31) continue;
    #pragma unroll
    for (int kx = 0; kx < 3; ++kx) {
      int xx = x + kx - 1;
      if (xx < 0 || xx > 31) continue;
      int p = yy * 32 + xx;
      acc += m[p] * w[ky * 3 + kx];
      acc += (s[p] + g[p]) * w[9 + ky * 3 + kx];
    }
  }
  hbuf[tid] = fmaxf(acc, 0.0f);
}

// ---------------- conv2 (32->1 ch, 3x3 SAME) + sigmoid ----------------
__global__ __launch_bounds__(256) void conv2_sig(
    const float* __restrict__ hbuf, const float* __restrict__ w2,
    const float* __restrict__ b2, float* __restrict__ cost_out) {
  int tid = blockIdx.x * 256 + threadIdx.x;       // 65536 threads
  int pix = tid & 1023;
  int b   = tid >> 10;
  int y = pix >> 5, x = pix & 31;
  const float* hb = hbuf + b * 32 * HW;
  float acc = b2[0];
  for (int ic = 0; ic < 32; ++ic) {
    const float* hc = hb + ic * HW;
    const float* w  = w2 + ic * 9;
    #pragma unroll
    for (int ky = 0; ky < 3; ++ky) {
      int yy = y + ky - 1;
      if (yy < 0 || yy > 31) continue;
      #pragma unroll
      for (int kx = 0; kx < 3; ++kx) {
        int xx = x + kx - 1;
        if (xx < 0 || xx > 31) continue;
        acc += hc[yy * 32 + xx] * w[ky * 3 + kx];
      }
    }
  }
  cost_out[tid] = 1.0f / (1.0f + expf(-acc));
}

// ---------------- differentiable A* forward (exact discrete semantics) ---------
// One block (256 thr = 4 waves) per batch; 4 cells per lane.
__global__ __launch_bounds__(256) void astar_kernel(
    const float* __restrict__ cost_all,  // pred cost maps [64][1024]
    const float* __restrict__ maps,      // obstacles (1 = free)
    const float* __restrict__ start,
    const float* __restrict__ goal,
    float* __restrict__ out_hist,
    float* __restrict__ out_path) {
  __shared__ float g_lds[HW];
  __shared__ float cost_lds[HW];
  __shared__ unsigned short par_lds[HW];
  __shared__ unsigned long long red[4];
  __shared__ int gidx_sh;
  __shared__ unsigned char path_sh[HW];

  const int t = threadIdx.x;
  const int b = blockIdx.x;
  const int base = t * 4;
  const float C_INV = 0.17677669529663687f;   // float32(1/sqrt(32)), matches jnp weak promote

  const float* cost_p  = cost_all + b * HW;
  const float* obs_p   = maps     + b * HW;
  const float* start_p = start    + b * HW;
  const float* goal_p  = goal     + b * HW;

  // ---- init ----
  float4 c4 = *reinterpret_cast<const float4*>(cost_p + base);
  float cst[4] = {c4.x, c4.y, c4.z, c4.w};
  int obs_m = 0, open_m = 0, hist_m = 0;
  #pragma unroll
  for (int j = 0; j < 4; ++j) {
    int cell = base + j;
    if (obs_p[cell] != 0.0f)   obs_m  |= 1 << j;
    if (start_p[cell] > 0.5f)  open_m |= 1 << j;
    if (goal_p[cell] > 0.5f)   gidx_sh = cell;   // one-hot: single writer
    cost_lds[cell] = cst[j];
    g_lds[cell] = 0.0f;
  }
  __syncthreads();
  const int goal_idx = gidx_sh;
  const int gy = goal_idx >> 5, gx = goal_idx & 31;

  float g4[4] = {0.0f, 0.0f, 0.0f, 0.0f};
  float h4[4];
  #pragma unroll
  for (int j = 0; j < 4; ++j) {
    int cell = base + j;
    int y = cell >> 5, x = cell & 31;
    int dy = y - gy; dy = dy < 0 ? -dy : dy;
    int dx = x - gx; dx = dx < 0 ? -dx : dx;
    // h = (min+max) + 0.001*sqrt(dy^2+dx^2), each op rounded exactly like np f32
    float e = sqrtf((float)(dy * dy + dx * dx));
    float heur = __fadd_rn((float)(dy + dx), __fmul_rn(0.001f, e));
    h4[j] = __fadd_rn(heur, cst[j]);             // + cost (done once in reference)
    par_lds[cell] = (unsigned short)goal_idx;    // parents0 = goal_idx
  }
  __syncthreads();

  // ---- 256 sequential A* steps ----
  for (int step = 0; step < 256; ++step) {
    // v = exp(-f/sqrt(32)) * open ; local argmax (first-index on ties)
    float bv; int bc;
    {
      float v[4];
      #pragma unroll
      for (int j = 0; j < 4; ++j) {
        float f = 0.5f * (g4[j] + h4[j]);        // ==0.5*g+0.5*h exactly (pow2 scale)
        float ex = expf(__fmul_rn(-f, C_INV));
        v[j] = ((open_m >> j) & 1) ? ex : 0.0f;
      }
      bv = v[0]; bc = base;
      #pragma unroll
      for (int j = 1; j < 4; ++j)
        if (v[j] > bv) { bv = v[j]; bc = base + j; }
    }
    // pack (value, ~cell) so max-key == (max v, min cell) == jnp.argmax semantics
    unsigned long long key =
        ((unsigned long long)__float_as_uint(bv) << 32) |
        (unsigned long long)(0xFFFFFFFFu - (unsigned)bc);
    #pragma unroll
    for (int off = 1; off < 64; off <<= 1) {
      unsigned long long o = __shfl_xor(key, off, 64);
      if (o > key) key = o;
    }
    if ((t & 63) == 0) red[t >> 6] = key;
    __syncthreads();
    {
      unsigned long long k;
      k = red[0];
      if (red[1] > k) k = red[1];
      if (red[2] > k) k = red[2];
      if (red[3] > k) k = red[3];
      key = k;
    }
    const int sel = (int)(0xFFFFFFFFu - (unsigned)(key & 0xFFFFFFFFu));
    const bool unsolved = (sel != goal_idx);
    const float gsum = g_lds[sel] + cost_lds[sel];   // g2 value for all 8 neighbors

    // hist[sel]=1 ; open[sel]-=unsolved  (sel is never its own neighbor)
    {
      int lj = sel - base;
      if (lj >= 0 && lj < 4) {
        hist_m |= 1 << lj;
        if (unsolved) open_m &= ~(1 << lj);
      }
    }
    // neighbor relax
    const int ys = sel >> 5, xs = sel & 31;
    #pragma unroll
    for (int j = 0; j < 4; ++j) {
      int cell = base + j;
      int y = cell >> 5, x = cell & 31;
      int dy = y - ys; dy = dy < 0 ? -dy : dy;
      int dx = x - xs; dx = dx < 0 ? -dx : dx;
      bool isnbr = (dy <= 1) && (dx <= 1) && ((dy + dx) > 0);
      bool ob = (obs_m  >> j) & 1;
      bool op = (open_m >> j) & 1;
      bool hi = (hist_m >> j) & 1;
      bool idxb = isnbr && ob && ((!op && !hi) || (op && (g4[j] > gsum)));
      if (idxb) {
        g4[j] = gsum;
        open_m |= 1 << j;
        par_lds[cell] = (unsigned short)sel;
      }
    }
    // publish my g cells (unchanged values for untouched cells -> benign)
    *reinterpret_cast<float4*>(g_lds + base) = make_float4(g4[0], g4[1], g4[2], g4[3]);
    __syncthreads();
  }

  // ---- backtrack (early-exit on revisit is exact: parent table is static) ----
  *reinterpret_cast<uchar4*>(path_sh + base) = make_uchar4(0, 0, 0, 0);
  __syncthreads();
  if (t == 0) {
    path_sh[goal_idx] = 1;
    int loc = par_lds[goal_idx];
    for (int i = 0; i < 255; ++i) {
      if (path_sh[loc]) break;
      path_sh[loc] = 1;
      loc = par_lds[loc];
    }
  }
  __syncthreads();

  // ---- outputs ----
  float hv[4], pv[4];
  #pragma unroll
  for (int j = 0; j < 4; ++j) {
    hv[j] = ((hist_m >> j) & 1) ? 1.0f : 0.0f;
    pv[j] = path_sh[base + j] ? 1.0f : 0.0f;
  }
  *reinterpret_cast<float4*>(out_hist + b * HW + base) = make_float4(hv[0], hv[1], hv[2], hv[3]);
  *reinterpret_cast<float4*>(out_path + b * HW + base) = make_float4(pv[0], pv[1], pv[2], pv[3]);
}

extern "C" void kernel_launch(void* const* d_in, const int* in_sizes, int n_in,
                              void* d_out, int out_size, void* d_ws, size_t ws_size,
                              hipStream_t stream) {
  const float* maps  = (const float*)d_in[0];
  const float* start = (const float*)d_in[1];
  const float* goal  = (const float*)d_in[2];
  const float* w1    = (const float*)d_in[3];
  const float* b1    = (const float*)d_in[4];
  const float* w2    = (const float*)d_in[5];
  const float* b2    = (const float*)d_in[6];

  float* out      = (float*)d_out;
  float* out_hist = out;               // histories
  float* out_path = out + 64 * HW;     // paths
  float* out_cost = out + 128 * HW;    // pred_cost_maps

  float* hbuf = (float*)d_ws;          // 64*32*1024 floats = 8 MB scratch

  conv1_relu<<<8192, 256, 0, stream>>>(maps, start, goal, w1, b1, hbuf);
  conv2_sig<<<256, 256, 0, stream>>>(hbuf, w2, b2, out_cost);
  astar_kernel<<<64, 256, 0, stream>>>(out_cost, maps, start, goal, out_hist, out_path);
}

// Round 3
// 276.402 us; speedup vs baseline: 1.4010x; 1.4010x over previous
//
#include <hip/hip_runtime.h>

// B=64, H=W=32, HW=1024, steps=256, backtrack 255.
// Outputs: [histories 65536][paths 65536][pred_cost 65536] float32.
// Single fused kernel: 64 blocks (1 per batch) x 256 threads.
//   Phase 1 (all 256 thr): conv1(2->32)+ReLU, conv2(32->1)+sigmoid, channel-tiled
//            8-ch hidden slabs in LDS (bit-identical accumulation order to the
//            round-1 kernels that passed with absmax 0.0; zero-padded taps add
//            exact +0 terms, bit-safe).
//   Phase 2 (wave 0 only, barrier-free): 256 A* steps. Per step: lane-local
//            16-key max tree -> DPP wave max (ROW_SHR 1/2/4/8 + row_bcast15/31,
//            result in lane 63 — the canonical AMD sequence; row_shl was the
//            round-2 bug: it accumulates into lane 0, not 15/47) -> readlane 63
//            -> uniform-addr gsum read -> per-lane <=2 neighbor relax (relax
//            lanes are exactly the owner lanes of their target cells).
//   Phase 3 (all): backtrack (lane 0) + output writes.

#define HW 1024

// DPP wave-64 max-reduce step on a u64 key (hi=value bits, lo=1023-cell).
// update_dpp(old=own, src=own, ctrl, row_mask=0xf, bank_mask=0xf, bound_ctrl=0):
// non-receiving/invalid lanes keep their own value (identity for max).
#define DPP_MAX64(key, ctrl) do {                                              \
    unsigned int _lo = (unsigned int)(key);                                    \
    unsigned int _hi = (unsigned int)((key) >> 32);                            \
    unsigned int _slo = (unsigned int)__builtin_amdgcn_update_dpp(             \
        (int)_lo, (int)_lo, (ctrl), 0xf, 0xf, false);                          \
    unsigned int _shi = (unsigned int)__builtin_amdgcn_update_dpp(             \
        (int)_hi, (int)_hi, (ctrl), 0xf, 0xf, false);                          \
    unsigned long long _o = ((unsigned long long)_shi << 32) | _slo;           \
    if (_o > (key)) (key) = _o;                                                \
} while (0)

__global__ __launch_bounds__(256) void fused_nastar(
    const float* __restrict__ maps, const float* __restrict__ start,
    const float* __restrict__ goal, const float* __restrict__ w1,
    const float* __restrict__ b1, const float* __restrict__ w2,
    const float* __restrict__ b2, float* __restrict__ out_hist,
    float* __restrict__ out_path, float* __restrict__ out_cost) {
  __shared__ float hid[8][HW];            // 32 KB: 8-channel hidden slab
  __shared__ float cost_sh[HW];           // 4 KB
  __shared__ float2 gc[HW];               // 8 KB: {g, cost} per cell
  __shared__ unsigned int vkey[HW];       // 4 KB: float bits of v (0 if closed)
  __shared__ float hpc[HW];               // 4 KB: heuristic + cost (h4)
  __shared__ int flags[HW];               // 4 KB: bit0 obs, bit1 open, bit2 hist
  __shared__ unsigned short par[HW];      // 2 KB
  __shared__ unsigned char path_sh[HW];   // 1 KB
  // total ~59.4 KB

  const int t = threadIdx.x;
  const int b = blockIdx.x;
  const float C_INV = 0.17677669529663687f;  // float32(1/sqrt(32))

  const float* m_p = maps  + b * HW;
  const float* s_p = start + b * HW;
  const float* g_p = goal  + b * HW;

  // ---------------- Phase 1: encoder ----------------
  const int base = t * 4;
  float acc2[4] = {b2[0], b2[0], b2[0], b2[0]};
  for (int grp = 0; grp < 4; ++grp) {
    // conv1 for oc in [8*grp, 8*grp+8)
    #pragma unroll
    for (int p = 0; p < 4; ++p) {
      int pix = base + p;
      int y = pix >> 5, x = pix & 31;
      float win0[9], win1[9];
      #pragma unroll
      for (int ky = 0; ky < 3; ++ky) {
        #pragma unroll
        for (int kx = 0; kx < 3; ++kx) {
          int yy = y + ky - 1, xx = x + kx - 1;
          bool ok = (yy >= 0) && (yy <= 31) && (xx >= 0) && (xx <= 31);
          int q = ok ? yy * 32 + xx : 0;
          float v0 = m_p[q];
          float v1 = s_p[q] + g_p[q];
          win0[ky * 3 + kx] = ok ? v0 : 0.0f;
          win1[ky * 3 + kx] = ok ? v1 : 0.0f;
        }
      }
      #pragma unroll
      for (int ocl = 0; ocl < 8; ++ocl) {
        int oc = grp * 8 + ocl;
        const float* w = w1 + oc * 18;
        float acc = b1[oc];
        #pragma unroll
        for (int k = 0; k < 9; ++k) {
          acc += win0[k] * w[k];       // same op order as round-1 conv1
          acc += win1[k] * w[9 + k];
        }
        hid[ocl][pix] = fmaxf(acc, 0.0f);
      }
    }
    __syncthreads();
    // conv2 partial accumulate (ic ascending across groups, taps inner: the
    // exact round-1 summation order)
    #pragma unroll
    for (int p = 0; p < 4; ++p) {
      int pix = base + p;
      int y = pix >> 5, x = pix & 31;
      float a = acc2[p];
      #pragma unroll
      for (int ocl = 0; ocl < 8; ++ocl) {
        int ic = grp * 8 + ocl;
        const float* w = w2 + ic * 9;
        #pragma unroll
        for (int ky = 0; ky < 3; ++ky) {
          #pragma unroll
          for (int kx = 0; kx < 3; ++kx) {
            int yy = y + ky - 1, xx = x + kx - 1;
            bool ok = (yy >= 0) && (yy <= 31) && (xx >= 0) && (xx <= 31);
            int q = ok ? yy * 32 + xx : 0;
            float hv = hid[ocl][q];
            a += (ok ? hv : 0.0f) * w[ky * 3 + kx];
          }
        }
      }
      acc2[p] = a;
    }
    __syncthreads();
  }
  float cost4[4];
  #pragma unroll
  for (int p = 0; p < 4; ++p) {
    cost4[p] = 1.0f / (1.0f + expf(-acc2[p]));   // identical to round-1
    cost_sh[base + p] = cost4[p];
  }
  *reinterpret_cast<float4*>(out_cost + b * HW + base) =
      make_float4(cost4[0], cost4[1], cost4[2], cost4[3]);
  __syncthreads();

  // ---------------- Phase 2: A* (wave 0 only, no barriers) ----------------
  if (t < 64) {
    const int lane = t;
    // zero path
    reinterpret_cast<int4*>(path_sh)[lane] = make_int4(0, 0, 0, 0);
    // find goal via ballot (one-hot)
    int myg = -1;
    #pragma unroll
    for (int j = 0; j < 16; ++j) {
      int cell = j * 64 + lane;
      if (g_p[cell] > 0.5f) myg = cell;
    }
    unsigned long long gm = __ballot(myg >= 0);
    int src_lane = (int)__ffsll(gm) - 1;
    const int goal_idx = __shfl(myg, src_lane, 64);
    const int gy = goal_idx >> 5, gx = goal_idx & 31;

    // init per-cell state
    #pragma unroll
    for (int j = 0; j < 16; ++j) {
      int cell = j * 64 + lane;
      int y = cell >> 5, x = cell & 31;
      float cst = cost_sh[cell];
      int dy = y - gy; dy = dy < 0 ? -dy : dy;
      int dx = x - gx; dx = dx < 0 ? -dx : dx;
      float e = sqrtf((float)(dy * dy + dx * dx));
      float heur = __fadd_rn((float)(dy + dx), __fmul_rn(0.001f, e));
      float hc = __fadd_rn(heur, cst);       // h4 = heuristic + cost
      hpc[cell] = hc;
      gc[cell] = make_float2(0.0f, cst);
      bool isobs = (m_p[cell] != 0.0f);
      bool isst  = (s_p[cell] > 0.5f);
      flags[cell] = (isobs ? 1 : 0) | (isst ? 2 : 0);
      float f = 0.5f * (0.0f + hc);          // g=0 at init, same expr as loop
      float ex = expf(__fmul_rn(-f, C_INV));
      vkey[cell] = isst ? __float_as_uint(ex) : 0u;
      par[cell] = (unsigned short)goal_idx;
    }

    const int x = lane & 31, half = lane >> 5;
    const unsigned int lowbase = 1023u - (unsigned)lane;  // low = lowbase - 64j

    for (int step = 0; step < 256; ++step) {
      // lane-local max over 16 cells: key = (v_bits<<32)|(1023-cell)
      unsigned long long k[16];
      #pragma unroll
      for (int j = 0; j < 16; ++j) {
        unsigned int v = vkey[j * 64 + lane];
        k[j] = ((unsigned long long)v << 32) | (lowbase - 64u * (unsigned)j);
      }
      #pragma unroll
      for (int s = 8; s >= 1; s >>= 1) {
        #pragma unroll
        for (int i = 0; i < s; ++i)
          if (k[i + s] > k[i]) k[i] = k[i + s];
      }
      unsigned long long key = k[0];
      // wave-64 DPP max reduce -> lane 63 (canonical row_shr sequence)
      DPP_MAX64(key, 0x111);  // row_shr:1
      DPP_MAX64(key, 0x112);  // row_shr:2
      DPP_MAX64(key, 0x114);  // row_shr:4
      DPP_MAX64(key, 0x118);  // row_shr:8
      DPP_MAX64(key, 0x142);  // row_bcast:15
      DPP_MAX64(key, 0x143);  // row_bcast:31
      unsigned int klo =
          (unsigned int)__builtin_amdgcn_readlane((int)(unsigned int)key, 63);
      const int sel = 1023 - (int)klo;

      float2 gcs = gc[sel];                  // uniform-addr broadcast read
      const float gsum = gcs.x + gcs.y;      // g2 value (exact, as reference)
      const bool unsolved = (sel != goal_idx);

      // owner: hist set; close if unsolved
      if ((sel & 63) == lane) {
        int fl = flags[sel];
        int nfl = fl | 4;
        if (unsolved) { nfl &= ~2; vkey[sel] = 0u; }
        flags[sel] = nfl;
      }

      // relax: each lane owns <=2 candidate neighbor cells
      const int xs = sel & 31, ys = sel >> 5;
      int dxs = x - xs; int adx = dxs < 0 ? -dxs : dxs;
      const bool act = (adx <= 1);
      const bool samep = (((ys ^ half) & 1) == 0);
      const int yA = samep ? ys : (ys - 1);
      const bool vAv = act && (samep ? (adx >= 1) : (yA >= 0));
      const int yB = ys + 1;
      const bool vBv = act && (!samep) && (yB <= 31);

      {
        int c = yA * 32 + x; int cc = vAv ? c : 0;
        int fl = flags[cc];
        float gcur = gc[cc].x;
        float hcv = hpc[cc];
        bool ob = fl & 1, op = fl & 2, hi = fl & 4;
        bool idx = vAv && ob && ((!op && !hi) || (op && (gcur > gsum)));
        if (idx) {
          gc[cc].x = gsum;
          float f = 0.5f * (gsum + hcv);
          vkey[cc] = __float_as_uint(expf(__fmul_rn(-f, C_INV)));
          flags[cc] = fl | 2;
          par[cc] = (unsigned short)sel;
        }
      }
      {
        int c = yB * 32 + x; int cc = vBv ? c : 0;
        int fl = flags[cc];
        float gcur = gc[cc].x;
        float hcv = hpc[cc];
        bool ob = fl & 1, op = fl & 2, hi = fl & 4;
        bool idx = vBv && ob && ((!op && !hi) || (op && (gcur > gsum)));
        if (idx) {
          gc[cc].x = gsum;
          float f = 0.5f * (gsum + hcv);
          vkey[cc] = __float_as_uint(expf(__fmul_rn(-f, C_INV)));
          flags[cc] = fl | 2;
          par[cc] = (unsigned short)sel;
        }
      }
    }

    // backtrack (parent table static; revisit => cycle => exact early exit)
    if (lane == 0) {
      path_sh[goal_idx] = 1;
      int loc = par[goal_idx];
      for (int i = 0; i < 255; ++i) {
        if (path_sh[loc]) break;
        path_sh[loc] = 1;
        loc = par[loc];
      }
    }
  }
  __syncthreads();

  // ---------------- Phase 3: outputs ----------------
  float hv[4], pv[4];
  #pragma unroll
  for (int p = 0; p < 4; ++p) {
    int cell = base + p;
    hv[p] = (float)((flags[cell] >> 2) & 1);
    pv[p] = (float)path_sh[cell];
  }
  *reinterpret_cast<float4*>(out_hist + b * HW + base) =
      make_float4(hv[0], hv[1], hv[2], hv[3]);
  *reinterpret_cast<float4*>(out_path + b * HW + base) =
      make_float4(pv[0], pv[1], pv[2], pv[3]);
}

extern "C" void kernel_launch(void* const* d_in, const int* in_sizes, int n_in,
                              void* d_out, int out_size, void* d_ws, size_t ws_size,
                              hipStream_t stream) {
  (void)in_sizes; (void)n_in; (void)d_ws; (void)ws_size; (void)out_size;
  const float* maps  = (const float*)d_in[0];
  const float* start = (const float*)d_in[1];
  const float* goal  = (const float*)d_in[2];
  const float* w1    = (const float*)d_in[3];
  const float* b1    = (const float*)d_in[4];
  const float* w2    = (const float*)d_in[5];
  const float* b2    = (const float*)d_in[6];

  float* out      = (float*)d_out;
  float* out_hist = out;
  float* out_path = out + 64 * HW;
  float* out_cost = out + 128 * HW;

  fused_nastar<<<64, 256, 0, stream>>>(maps, start, goal, w1, b1, w2, b2,
                                       out_hist, out_path, out_cost);
}